// Round 8
// baseline (78.817 us; speedup 1.0000x reference)
//
#include <hip/hip_runtime.h>

#define Bx 16
#define Gx 128
#define Nx 512
#define Px 4
#define Kx 3
#define Fx 128
#define NEG_SLOPE 0.2f
#define ZERO_TOL 1e-9f
#define BIGF 1.0e30f

typedef unsigned short u16;
typedef unsigned int u32;
typedef __bf16 v8bf __attribute__((ext_vector_type(8)));
typedef _Float16 v8hf __attribute__((ext_vector_type(8)));
typedef float v4f __attribute__((ext_vector_type(4)));

__device__ __forceinline__ u16 f2b(float f) {
  union { float f; u32 u; } v; v.f = f;
  u32 r = (v.u + 0x7fffu + ((v.u >> 16) & 1u)) >> 16;
  return (u16)r;
}
__device__ __forceinline__ u16 f2h(float f) {
  union { _Float16 h; u16 u; } v; v.h = (_Float16)f;
  return v.u;
}

// async global->LDS, 16B per lane; LDS dst must be wave-uniform base (+lane*16)
#define G2L16(gsrc, ldst)                                                     \
  __builtin_amdgcn_global_load_lds(                                           \
      (const __attribute__((address_space(1))) void*)(gsrc),                  \
      (__attribute__((address_space(3))) void*)(ldst), 16, 0, 0)

// ---------------------------------------------------------------------------
// prep: fused {mask | castx3 | castw16 | casth} by block range.
// blocks: [0,512) mask, [512,1536) castx3, [1536,1600) castw16, [1600,1792) casth
// ---------------------------------------------------------------------------
__global__ __launch_bounds__(256) void prep_kernel(const float* __restrict__ S,
                                                   const float* __restrict__ x,
                                                   const float* __restrict__ W,
                                                   const float* __restrict__ h,
                                                   u32* __restrict__ mb,
                                                   u16* __restrict__ xb,
                                                   u16* __restrict__ xTb,
                                                   u16* __restrict__ xT16,
                                                   u16* __restrict__ w16,
                                                   u16* __restrict__ Hb) {
  const int blk = blockIdx.x;
  const int tid = threadIdx.x;
  __shared__ float t[32][33];
  if (blk < 512) {
    const int wi = blk * 256 + tid;
    const float4* S4 = (const float4*)S;
    u32 bits = 0;
#pragma unroll
    for (int q = 0; q < 8; q++) {
      float4 v = S4[(size_t)wi * 8 + q];
      bits |= (fabsf(v.x) > ZERO_TOL ? 1u : 0u) << (q * 4);
      bits |= (fabsf(v.y) > ZERO_TOL ? 2u : 0u) << (q * 4);
      bits |= (fabsf(v.z) > ZERO_TOL ? 4u : 0u) << (q * 4);
      bits |= (fabsf(v.w) > ZERO_TOL ? 8u : 0u) << (q * 4);
    }
    mb[wi] = bits;
  } else if (blk < 1536) {
    const int idx = blk - 512;
    const int b = idx >> 6, g0 = ((idx >> 4) & 3) * 32, n0 = (idx & 15) * 32;
    const int r = tid >> 3, c4 = (tid & 7) * 4;
    const float* xp = x + (size_t)b * Gx * Nx;
    float4 v = *(const float4*)&xp[(g0 + r) * Nx + n0 + c4];
    ushort4 o;
    o.x = f2b(v.x); o.y = f2b(v.y); o.z = f2b(v.z); o.w = f2b(v.w);
    *(ushort4*)&xb[(size_t)b * Gx * Nx + (g0 + r) * Nx + n0 + c4] = o;
    t[r][c4 + 0] = v.x; t[r][c4 + 1] = v.y; t[r][c4 + 2] = v.z; t[r][c4 + 3] = v.w;
    __syncthreads();
    float tv[4] = {t[c4 + 0][r], t[c4 + 1][r], t[c4 + 2][r], t[c4 + 3][r]};
    ushort4 ob, oh;
    ob.x = f2b(tv[0]); oh.x = f2h(tv[0]);
    ob.y = f2b(tv[1]); oh.y = f2h(tv[1]);
    ob.z = f2b(tv[2]); oh.z = f2h(tv[2]);
    ob.w = f2b(tv[3]); oh.w = f2h(tv[3]);
    size_t off = (size_t)b * Nx * Gx + (size_t)(n0 + r) * Gx + g0 + c4;
    *(ushort4*)&xTb[off] = ob;
    *(ushort4*)&xT16[off] = oh;
  } else if (blk < 1600) {
    int i4 = ((blk - 1536) * 256 + tid) * 4;
    float4 v = *(const float4*)&W[i4];
    ushort4 o;
    o.x = f2h(v.x); o.y = f2h(v.y); o.z = f2h(v.z); o.w = f2h(v.w);
    *(ushort4*)&w16[i4] = o;
  } else {
    int i4 = ((blk - 1600) * 256 + tid) * 4;
    float4 v = *(const float4*)&h[i4];
    ushort4 o;
    o.x = f2b(v.x); o.y = f2b(v.y); o.z = f2b(v.z); o.w = f2b(v.w);
    *(ushort4*)&Hb[i4] = o;
  }
}

// ---------------------------------------------------------------------------
// wxt16: WxT[n][g] = sum_h xT[n][h] * W[g][h]  (fp16 MFMA, fp32 acc, fp16 out)
// grid (B*P, N/64), 256 thr (2x2 waves), block 64n x 128g, K=128 single-stage.
// ---------------------------------------------------------------------------
__global__ __launch_bounds__(256) void wxt16_kernel(const u16* __restrict__ xT16,
                                                    const u16* __restrict__ w16,
                                                    u16* __restrict__ WxT16) {
  __shared__ __align__(16) char smem[49152];
  constexpr int OB = 16384;
  const int bp = blockIdx.x, b = bp >> 2, p = bp & 3;
  const int rt = blockIdx.y;
  const int tid = threadIdx.x;
  const int w = tid >> 6, l = tid & 63;
  const int wr = w >> 1, wc = w & 1;
  const int lr = l & 15, ks = l >> 4;

  const u16* Ap = xT16 + ((size_t)b * Nx + rt * 64) * Gx;
  const u16* Bp = w16 + (size_t)p * Gx * Gx;
#pragma unroll
  for (int it = 0; it < 4; it++) {
    int chunk = it * 256 + w * 64 + l;
    int r = chunk >> 4, kq = l & 15;
    int kg = (kq ^ (r & 15)) * 8;
    G2L16(Ap + (size_t)r * Gx + kg, smem + it * 4096 + w * 1024);
  }
#pragma unroll
  for (int it = 0; it < 8; it++) {
    int chunk = it * 256 + w * 64 + l;
    int r = chunk >> 4, kq = l & 15;
    int kg = (kq ^ (r & 15)) * 8;
    G2L16(Bp + (size_t)r * Gx + kg, smem + OB + it * 4096 + w * 1024);
  }
  __syncthreads();

  v4f acc[2][4];
#pragma unroll
  for (int fr = 0; fr < 2; fr++)
#pragma unroll
    for (int fc = 0; fc < 4; fc++) acc[fr][fc] = (v4f){0.f, 0.f, 0.f, 0.f};

#pragma unroll
  for (int t = 0; t < 4; t++) {
    int kk = t * 4 + ks;
    v8hf ah[2];
#pragma unroll
    for (int fr = 0; fr < 2; fr++) {
      int ra = wr * 32 + fr * 16 + lr;
      ah[fr] = *(const v8hf*)(smem + ra * 256 + ((kk ^ (ra & 15)) * 16));
    }
#pragma unroll
    for (int fc = 0; fc < 4; fc++) {
      int rb = wc * 64 + fc * 16 + lr;
      v8hf bh = *(const v8hf*)(smem + OB + rb * 256 + ((kk ^ (rb & 15)) * 16));
#pragma unroll
      for (int fr = 0; fr < 2; fr++)
        acc[fr][fc] = __builtin_amdgcn_mfma_f32_16x16x32_f16(ah[fr], bh, acc[fr][fc], 0, 0, 0);
    }
  }

  u16* op = WxT16 + (size_t)bp * Nx * Gx;
#pragma unroll
  for (int fr = 0; fr < 2; fr++)
#pragma unroll
    for (int fc = 0; fc < 4; fc++) {
      int n = rt * 64 + wr * 32 + fr * 16 + ks * 4;
      int g = wc * 64 + fc * 16 + lr;
#pragma unroll
      for (int q = 0; q < 4; q++) op[(size_t)(n + q) * Gx + g] = f2h(acc[fr][fc][q]);
    }
}

// ---------------------------------------------------------------------------
// attn5: scores[i][j] = sum_g xT16[i][g]*WxT16[j][g] (fp16 MFMA);
// A in REGISTERS (32 VGPR), B double-buffered in LDS, ONE barrier per K-iter
// (gnt-verified pattern). leaky, mask, softmax over j, direct stores.
// grid (B*P, N/64), 512 thr (2 wr x 4 wc). Block: 64 i x 512 j, K=128.
// LDS 70 KB -> 2 blocks/CU; __launch_bounds__(512,4) caps VGPR<=128.
// ---------------------------------------------------------------------------
__global__ __launch_bounds__(512, 4) void attn5_kernel(const u16* __restrict__ xT16,
                                                       const u16* __restrict__ WxT16,
                                                       const u32* __restrict__ mb,
                                                       u16* __restrict__ aijT) {
  __shared__ __align__(16) char smem[71680];  // B0 32K | B1 32K | mask 4K | red 2K
  constexpr int OMBS = 65536, ORED = 69632;
  const int bp = blockIdx.x, b = bp >> 2;
  const int i0 = blockIdx.y * 64;
  const int tid = threadIdx.x;
  const int w = tid >> 6, l = tid & 63;
  const int wr = w >> 2, wc = w & 3;
  const int lr = l & 15, ks = l >> 4;

  {  // mask rows -> LDS (64 rows x 16 words)
    const u32* mbp = mb + ((size_t)b * Nx + i0) * 16;
    u32* mbs = (u32*)(smem + OMBS);
    mbs[tid] = mbp[tid];
    mbs[tid + 512] = mbp[tid + 512];
  }
  {  // stage A (16 KB) into buf0, chunk-XOR (r&15)
    const u16* Ap = xT16 + ((size_t)b * Nx + i0) * Gx;
#pragma unroll
    for (int it = 0; it < 2; it++) {
      int chunk = it * 512 + w * 64 + l;
      int r = chunk >> 4, kq = l & 15;
      int kg = (kq ^ (r & 15)) * 8;
      G2L16(Ap + (size_t)r * Gx + kg, smem + it * 8192 + w * 1024);
    }
  }
  __syncthreads();  // A (and mask) landed

  // A -> registers: areg[fr][t], t = K-iter (kk = t*4 + ks)
  v8hf areg[2][4];
#pragma unroll
  for (int fr = 0; fr < 2; fr++) {
    int ra = wr * 32 + fr * 16 + lr;
#pragma unroll
    for (int t = 0; t < 4; t++) {
      int kk = t * 4 + ks;
      areg[fr][t] = *(const v8hf*)(smem + ra * 256 + ((kk ^ (ra & 15)) * 16));
    }
  }
  __syncthreads();  // all waves done reading A from buf0

  const u16* Bp = WxT16 + (size_t)bp * Nx * Gx;
  auto STAGE_B = [&](int t) {
    char* dst = smem + (t & 1) * 32768;
    int g0 = t * 32;
#pragma unroll
    for (int it = 0; it < 4; it++) {
      int chunk = it * 512 + w * 64 + l;
      int r = chunk >> 2, kq = l & 3;
      int kg = (kq ^ (r & 3)) * 8;
      G2L16(Bp + (size_t)r * Gx + g0 + kg, dst + it * 8192 + w * 1024);
    }
  };

  v4f acc[2][8];
#pragma unroll
  for (int fr = 0; fr < 2; fr++)
#pragma unroll
    for (int fc = 0; fc < 8; fc++) acc[fr][fc] = (v4f){0.f, 0.f, 0.f, 0.f};

  STAGE_B(0);
  for (int t = 0; t < 4; t++) {
    __syncthreads();  // drains vmcnt: B_t landed; all waves done with buf[t^1]
    if (t < 3) STAGE_B(t + 1);
    const char* bb = smem + (t & 1) * 32768;
#pragma unroll
    for (int fc = 0; fc < 8; fc++) {
      int rb = wc * 128 + fc * 16 + lr;
      v8hf bh = *(const v8hf*)(bb + rb * 64 + ((ks ^ (rb & 3)) * 16));
#pragma unroll
      for (int fr = 0; fr < 2; fr++)
        acc[fr][fc] = __builtin_amdgcn_mfma_f32_16x16x32_f16(areg[fr][t], bh, acc[fr][fc], 0, 0, 0);
    }
  }

  u32* mbs = (u32*)(smem + OMBS);
  float* red0 = (float*)(smem + ORED);
  float* red1 = red0 + 256;

  // pass 1: masked leaky-relu + cross-wave row max partials
#pragma unroll
  for (int fr = 0; fr < 2; fr++)
#pragma unroll
    for (int q = 0; q < 4; q++) {
      int row = wr * 32 + fr * 16 + ks * 4 + q;
      float m = -BIGF;
#pragma unroll
      for (int fc = 0; fc < 8; fc++) {
        u32 word = mbs[row * 16 + wc * 4 + (fc >> 1)];
        int bit = ((fc & 1) << 4) + lr;
        float v = acc[fr][fc][q];
        v = v >= 0.f ? v : NEG_SLOPE * v;
        v = ((word >> bit) & 1u) ? v : -BIGF;
        acc[fr][fc][q] = v;
        m = fmaxf(m, v);
      }
      m = fmaxf(m, __shfl_xor(m, 1, 64));
      m = fmaxf(m, __shfl_xor(m, 2, 64));
      m = fmaxf(m, __shfl_xor(m, 4, 64));
      m = fmaxf(m, __shfl_xor(m, 8, 64));
      if (lr == 0) red0[row * 4 + wc] = m;
    }
  __syncthreads();
  // pass 2: global max, exp, cross-wave row sum partials
#pragma unroll
  for (int fr = 0; fr < 2; fr++)
#pragma unroll
    for (int q = 0; q < 4; q++) {
      int row = wr * 32 + fr * 16 + ks * 4 + q;
      float4 pm = *(const float4*)&red0[row * 4];
      float gm = fmaxf(fmaxf(pm.x, pm.y), fmaxf(pm.z, pm.w));
      float s = 0.f;
#pragma unroll
      for (int fc = 0; fc < 8; fc++) {
        float v = acc[fr][fc][q];
        float e = (v <= -0.5f * BIGF) ? 0.f : __expf(v - gm);
        acc[fr][fc][q] = e;
        s += e;
      }
      s += __shfl_xor(s, 1, 64);
      s += __shfl_xor(s, 2, 64);
      s += __shfl_xor(s, 4, 64);
      s += __shfl_xor(s, 8, 64);
      if (lr == 0) red1[row * 4 + wc] = s;
    }
  __syncthreads();
  // pass 3: normalize + direct ushort4 stores (4 consecutive i per lane)
  u16* dst = aijT + (size_t)bp * Nx * Nx + i0;
#pragma unroll
  for (int fr = 0; fr < 2; fr++) {
    int rbase = wr * 32 + fr * 16 + ks * 4;
    float inv[4];
#pragma unroll
    for (int q = 0; q < 4; q++) {
      float4 ps = *(const float4*)&red1[(rbase + q) * 4];
      float tot = (ps.x + ps.y) + (ps.z + ps.w);
      inv[q] = tot > 0.f ? 1.f / tot : 0.f;
    }
#pragma unroll
    for (int fc = 0; fc < 8; fc++) {
      int j = wc * 128 + fc * 16 + lr;
      ushort4 pk;
      pk.x = f2b(acc[fr][fc][0] * inv[0]);
      pk.y = f2b(acc[fr][fc][1] * inv[1]);
      pk.z = f2b(acc[fr][fc][2] * inv[2]);
      pk.w = f2b(acc[fr][fc][3] * inv[3]);
      *(ushort4*)&dst[(size_t)j * Nx + rbase] = pk;
    }
  }
}

// ---------------------------------------------------------------------------
// NT-GEMM core (r7-verified): 2-phase double-buffered, one barrier per K-iter.
// MODE 0: hop1  A=aijT(bp)  B=xb(b)    -> z1[g][m] + z1T[m][g]
// MODE 1: hop2  A=z1(bp)    B=aijT(bp) -> z2T[m][g]
// MODE 2: filt  A={xTb,z1T,z2T} segs  B=Hb(p) -> out[f][n] fp32 (+bias, relu)
// ---------------------------------------------------------------------------
template <int MODE>
__global__ __launch_bounds__(256) void gnt_kernel(const u16* __restrict__ pA,
                                                  const u16* __restrict__ pB,
                                                  const u16* __restrict__ pC,
                                                  const u16* __restrict__ pHb,
                                                  u16* __restrict__ o1,
                                                  u16* __restrict__ o2,
                                                  float* __restrict__ oF,
                                                  const float* __restrict__ bias) {
  __shared__ __align__(16) char smem[2][12288];
  const int bp = blockIdx.x;
  const int b = bp >> 2, p = bp & 3;
  const int by = blockIdx.y;
  const int rt = (MODE == 1) ? (by >> 2) : by;
  const int ct = (MODE == 1) ? (by & 3) : 0;
  const int tid = threadIdx.x;
  const int w = tid >> 6, l = tid & 63;
  const int wr = w >> 1, wc = w & 1;
  const int lr = l & 15, kslot = l >> 4;

  constexpr int KTOT = (MODE == 2) ? (Kx * Gx) : Nx;
  constexpr int SA = (MODE == 2) ? Gx : Nx;
  constexpr int SB = (MODE == 2) ? (Kx * Gx) : Nx;
  constexpr int NT = KTOT / 32;

  const u16* Abase;
  const u16* Bbase;
  if (MODE == 0) {
    Abase = pA + (size_t)bp * Nx * Nx + (size_t)rt * 64 * Nx;
    Bbase = pB + (size_t)b * Gx * Nx;
  } else if (MODE == 1) {
    Abase = pA + (size_t)bp * Gx * Nx + (size_t)rt * 64 * Nx;
    Bbase = pB + (size_t)bp * Nx * Nx + (size_t)ct * 128 * Nx;
  } else {
    Abase = nullptr;
    Bbase = pHb + (size_t)p * Fx * (Kx * Gx);
  }

  const int sar = tid >> 2;
  const int sakg = (tid & 3) ^ (sar & 3);
  const int sbr0 = tid >> 2, sbkg0 = (tid & 3) ^ (sbr0 & 3);
  const int sbr1 = (tid + 256) >> 2, sbkg1 = (tid & 3) ^ (sbr1 & 3);

  int aoff[2], boff[4];
#pragma unroll
  for (int fr = 0; fr < 2; fr++) {
    int row = wr * 32 + fr * 16 + lr;
    aoff[fr] = row * 64 + ((kslot ^ (row & 3)) * 16);
  }
#pragma unroll
  for (int fc = 0; fc < 4; fc++) {
    int row = wc * 64 + fc * 16 + lr;
    boff[fc] = 4096 + row * 64 + ((kslot ^ (row & 3)) * 16);
  }

  auto STAGE = [&](int bufi, int k0) {
    const u16* Aseg;
    int kin;
    if (MODE == 2) {
      int seg = k0 >> 7;
      kin = k0 & 127;
      const u16* base = (seg == 0) ? (pA + (size_t)b * Nx * Gx)
                       : (seg == 1) ? (pB + (size_t)bp * Nx * Gx)
                                    : (pC + (size_t)bp * Nx * Gx);
      Aseg = base + (size_t)rt * 64 * Gx;
    } else {
      Aseg = Abase;
      kin = k0;
    }
    char* base = smem[bufi];
    G2L16(Aseg + (size_t)sar * SA + kin + sakg * 8, base + w * 1024);
    G2L16(Bbase + (size_t)sbr0 * SB + k0 + sbkg0 * 8, base + 4096 + w * 1024);
    G2L16(Bbase + (size_t)sbr1 * SB + k0 + sbkg1 * 8, base + 8192 + w * 1024);
  };

  v4f acc[2][4];
#pragma unroll
  for (int fr = 0; fr < 2; fr++)
#pragma unroll
    for (int fc = 0; fc < 4; fc++) acc[fr][fc] = (v4f){0.f, 0.f, 0.f, 0.f};

  STAGE(0, 0);
  int cur = 0;
  for (int t = 0; t < NT; t++) {
    __syncthreads();
    if (t + 1 < NT) STAGE(cur ^ 1, (t + 1) * 32);
    const char* bb = smem[cur];
    v8bf af[2], bf4[4];
#pragma unroll
    for (int fr = 0; fr < 2; fr++) af[fr] = *(const v8bf*)(bb + aoff[fr]);
#pragma unroll
    for (int fc = 0; fc < 4; fc++) bf4[fc] = *(const v8bf*)(bb + boff[fc]);
#pragma unroll
    for (int fr = 0; fr < 2; fr++)
#pragma unroll
      for (int fc = 0; fc < 4; fc++)
        acc[fr][fc] = __builtin_amdgcn_mfma_f32_16x16x32_bf16(af[fr], bf4[fc],
                                                              acc[fr][fc], 0, 0, 0);
    cur ^= 1;
  }

  if (MODE == 0) {
    u16* z1p = o1 + (size_t)bp * Gx * Nx;
    u16* z1Tp = o2 + (size_t)bp * Nx * Gx;
#pragma unroll
    for (int fr = 0; fr < 2; fr++)
#pragma unroll
      for (int fc = 0; fc < 4; fc++) {
        int m0 = rt * 64 + wr * 32 + fr * 16 + kslot * 4;
        int g = wc * 64 + fc * 16 + lr;
        v4f a = acc[fr][fc];
        ushort4 pk;
        pk.x = f2b(a[0]); pk.y = f2b(a[1]); pk.z = f2b(a[2]); pk.w = f2b(a[3]);
        *(ushort4*)&z1p[(size_t)g * Nx + m0] = pk;
        z1Tp[(size_t)(m0 + 0) * Gx + g] = pk.x;
        z1Tp[(size_t)(m0 + 1) * Gx + g] = pk.y;
        z1Tp[(size_t)(m0 + 2) * Gx + g] = pk.z;
        z1Tp[(size_t)(m0 + 3) * Gx + g] = pk.w;
      }
  } else if (MODE == 1) {
    u16* z2Tp = o1 + (size_t)bp * Nx * Gx;
#pragma unroll
    for (int fr = 0; fr < 2; fr++)
#pragma unroll
      for (int fc = 0; fc < 4; fc++) {
        int g0r = rt * 64 + wr * 32 + fr * 16 + kslot * 4;
        int m = ct * 128 + wc * 64 + fc * 16 + lr;
        v4f a = acc[fr][fc];
        ushort4 pk;
        pk.x = f2b(a[0]); pk.y = f2b(a[1]); pk.z = f2b(a[2]); pk.w = f2b(a[3]);
        *(ushort4*)&z2Tp[(size_t)m * Gx + g0r] = pk;
      }
  } else {
    float* op = oF + (size_t)(b * Px + p) * Fx * Nx;
#pragma unroll
    for (int fc = 0; fc < 4; fc++) {
      int f = wc * 64 + fc * 16 + lr;
      float bi = bias[f];
#pragma unroll
      for (int fr = 0; fr < 2; fr++) {
        int n0 = rt * 64 + wr * 32 + fr * 16 + kslot * 4;
        v4f a = acc[fr][fc];
        float4 o;
        o.x = fmaxf(a[0] + bi, 0.f);
        o.y = fmaxf(a[1] + bi, 0.f);
        o.z = fmaxf(a[2] + bi, 0.f);
        o.w = fmaxf(a[3] + bi, 0.f);
        *(float4*)&op[(size_t)f * Nx + n0] = o;
      }
    }
  }
}

// ---------------------------------------------------------------------------
extern "C" void kernel_launch(void* const* d_in, const int* in_sizes, int n_in,
                              void* d_out, int out_size, void* d_ws, size_t ws_size,
                              hipStream_t stream) {
  const float* x = (const float*)d_in[0];
  const float* S = (const float*)d_in[1];
  const float* W = (const float*)d_in[2];
  const float* h = (const float*)d_in[4];
  const float* bias = (const float*)d_in[5];
  float* out = (float*)d_out;

  char* ws = (char*)d_ws;
  u16* aijT  = (u16*)ws;                   // @ 0          33,554,432
  u16* WxT16 = (u16*)(ws + 33554432);      // @ 32M         8,388,608
  u16* xT16  = (u16*)(ws + 41943040);      // @ 40M         2,097,152
  u16* xTb   = (u16*)(ws + 44040192);      // @ 42M         2,097,152
  u16* xb    = (u16*)(ws + 46137344);      // @ 44M         2,097,152
  u16* z1    = (u16*)(ws + 48234496);      // @ 46M         8,388,608
  u16* z1T   = (u16*)(ws + 56623104);      // @ 54M         8,388,608
  u16* z2T   = (u16*)(ws + 65011712);      // @ 62M         8,388,608
  u16* Hb    = (u16*)(ws + 73400320);      // @ 70M           393,216
  u16* W16   = (u16*)(ws + 73793536);      //                 131,072
  u32* mb    = (u32*)(ws + 73924608);      //                 524,288

  prep_kernel<<<dim3(1792), 256, 0, stream>>>(S, x, W, h, mb, xb, xTb, xT16, W16, Hb);
  wxt16_kernel<<<dim3(Bx * Px, Nx / 64), 256, 0, stream>>>(xT16, W16, WxT16);
  attn5_kernel<<<dim3(Bx * Px, Nx / 64), 512, 0, stream>>>(xT16, WxT16, mb, aijT);
  gnt_kernel<0><<<dim3(Bx * Px, 8), 256, 0, stream>>>(aijT, xb, nullptr, nullptr,
                                                      z1, z1T, nullptr, nullptr);
  gnt_kernel<1><<<dim3(Bx * Px, 8), 256, 0, stream>>>(z1, aijT, nullptr, nullptr,
                                                      z2T, nullptr, nullptr, nullptr);
  gnt_kernel<2><<<dim3(Bx * Px, 8), 256, 0, stream>>>(xTb, z1T, z2T, Hb,
                                                      nullptr, nullptr, out, bias);
  (void)in_sizes; (void)n_in; (void)out_size; (void)ws_size;
}

// Round 9
// 77.076 us; speedup vs baseline: 1.0226x; 1.0226x over previous
//
#include <hip/hip_runtime.h>

#define Bx 16
#define Gx 128
#define Nx 512
#define Px 4
#define Kx 3
#define Fx 128
#define NEG_SLOPE 0.2f
#define ZERO_TOL 1e-9f
#define BIGF 1.0e30f

typedef unsigned short u16;
typedef unsigned int u32;
typedef __bf16 v8bf __attribute__((ext_vector_type(8)));
typedef _Float16 v8hf __attribute__((ext_vector_type(8)));
typedef float v4f __attribute__((ext_vector_type(4)));

__device__ __forceinline__ u16 f2b(float f) {
  union { float f; u32 u; } v; v.f = f;
  u32 r = (v.u + 0x7fffu + ((v.u >> 16) & 1u)) >> 16;
  return (u16)r;
}
__device__ __forceinline__ u16 f2h(float f) {
  union { _Float16 h; u16 u; } v; v.h = (_Float16)f;
  return v.u;
}

// async global->LDS, 16B per lane; LDS dst must be wave-uniform base (+lane*16)
#define G2L16(gsrc, ldst)                                                     \
  __builtin_amdgcn_global_load_lds(                                           \
      (const __attribute__((address_space(1))) void*)(gsrc),                  \
      (__attribute__((address_space(3))) void*)(ldst), 16, 0, 0)

// ---------------------------------------------------------------------------
// prep: fused {mask | castx3 | castw16 | casth} by block range.
// blocks: [0,512) mask, [512,1536) castx3, [1536,1600) castw16, [1600,1792) casth
// ---------------------------------------------------------------------------
__global__ __launch_bounds__(256) void prep_kernel(const float* __restrict__ S,
                                                   const float* __restrict__ x,
                                                   const float* __restrict__ W,
                                                   const float* __restrict__ h,
                                                   u32* __restrict__ mb,
                                                   u16* __restrict__ xb,
                                                   u16* __restrict__ xTb,
                                                   u16* __restrict__ xT16,
                                                   u16* __restrict__ w16,
                                                   u16* __restrict__ Hb) {
  const int blk = blockIdx.x;
  const int tid = threadIdx.x;
  __shared__ float t[32][33];
  if (blk < 512) {
    const int wi = blk * 256 + tid;
    const float4* S4 = (const float4*)S;
    u32 bits = 0;
#pragma unroll
    for (int q = 0; q < 8; q++) {
      float4 v = S4[(size_t)wi * 8 + q];
      bits |= (fabsf(v.x) > ZERO_TOL ? 1u : 0u) << (q * 4);
      bits |= (fabsf(v.y) > ZERO_TOL ? 2u : 0u) << (q * 4);
      bits |= (fabsf(v.z) > ZERO_TOL ? 4u : 0u) << (q * 4);
      bits |= (fabsf(v.w) > ZERO_TOL ? 8u : 0u) << (q * 4);
    }
    mb[wi] = bits;
  } else if (blk < 1536) {
    const int idx = blk - 512;
    const int b = idx >> 6, g0 = ((idx >> 4) & 3) * 32, n0 = (idx & 15) * 32;
    const int r = tid >> 3, c4 = (tid & 7) * 4;
    const float* xp = x + (size_t)b * Gx * Nx;
    float4 v = *(const float4*)&xp[(g0 + r) * Nx + n0 + c4];
    ushort4 o;
    o.x = f2b(v.x); o.y = f2b(v.y); o.z = f2b(v.z); o.w = f2b(v.w);
    *(ushort4*)&xb[(size_t)b * Gx * Nx + (g0 + r) * Nx + n0 + c4] = o;
    t[r][c4 + 0] = v.x; t[r][c4 + 1] = v.y; t[r][c4 + 2] = v.z; t[r][c4 + 3] = v.w;
    __syncthreads();
    float tv[4] = {t[c4 + 0][r], t[c4 + 1][r], t[c4 + 2][r], t[c4 + 3][r]};
    ushort4 ob, oh;
    ob.x = f2b(tv[0]); oh.x = f2h(tv[0]);
    ob.y = f2b(tv[1]); oh.y = f2h(tv[1]);
    ob.z = f2b(tv[2]); oh.z = f2h(tv[2]);
    ob.w = f2b(tv[3]); oh.w = f2h(tv[3]);
    size_t off = (size_t)b * Nx * Gx + (size_t)(n0 + r) * Gx + g0 + c4;
    *(ushort4*)&xTb[off] = ob;
    *(ushort4*)&xT16[off] = oh;
  } else if (blk < 1600) {
    int i4 = ((blk - 1536) * 256 + tid) * 4;
    float4 v = *(const float4*)&W[i4];
    ushort4 o;
    o.x = f2h(v.x); o.y = f2h(v.y); o.z = f2h(v.z); o.w = f2h(v.w);
    *(ushort4*)&w16[i4] = o;
  } else {
    int i4 = ((blk - 1600) * 256 + tid) * 4;
    float4 v = *(const float4*)&h[i4];
    ushort4 o;
    o.x = f2b(v.x); o.y = f2b(v.y); o.z = f2b(v.z); o.w = f2b(v.w);
    *(ushort4*)&Hb[i4] = o;
  }
}

// ---------------------------------------------------------------------------
// wxt16: WxT[n][g] = sum_h xT[n][h] * W[g][h]  (fp16 MFMA, fp32 acc, fp16 out)
// grid (B*P, N/64), 256 thr (2x2 waves), block 64n x 128g, K=128 single-stage.
// ---------------------------------------------------------------------------
__global__ __launch_bounds__(256) void wxt16_kernel(const u16* __restrict__ xT16,
                                                    const u16* __restrict__ w16,
                                                    u16* __restrict__ WxT16) {
  __shared__ __align__(16) char smem[49152];
  constexpr int OB = 16384;
  const int bp = blockIdx.x, b = bp >> 2, p = bp & 3;
  const int rt = blockIdx.y;
  const int tid = threadIdx.x;
  const int w = tid >> 6, l = tid & 63;
  const int wr = w >> 1, wc = w & 1;
  const int lr = l & 15, ks = l >> 4;

  const u16* Ap = xT16 + ((size_t)b * Nx + rt * 64) * Gx;
  const u16* Bp = w16 + (size_t)p * Gx * Gx;
#pragma unroll
  for (int it = 0; it < 4; it++) {
    int chunk = it * 256 + w * 64 + l;
    int r = chunk >> 4, kq = l & 15;
    int kg = (kq ^ (r & 15)) * 8;
    G2L16(Ap + (size_t)r * Gx + kg, smem + it * 4096 + w * 1024);
  }
#pragma unroll
  for (int it = 0; it < 8; it++) {
    int chunk = it * 256 + w * 64 + l;
    int r = chunk >> 4, kq = l & 15;
    int kg = (kq ^ (r & 15)) * 8;
    G2L16(Bp + (size_t)r * Gx + kg, smem + OB + it * 4096 + w * 1024);
  }
  __syncthreads();

  v4f acc[2][4];
#pragma unroll
  for (int fr = 0; fr < 2; fr++)
#pragma unroll
    for (int fc = 0; fc < 4; fc++) acc[fr][fc] = (v4f){0.f, 0.f, 0.f, 0.f};

#pragma unroll
  for (int t = 0; t < 4; t++) {
    int kk = t * 4 + ks;
    v8hf ah[2];
#pragma unroll
    for (int fr = 0; fr < 2; fr++) {
      int ra = wr * 32 + fr * 16 + lr;
      ah[fr] = *(const v8hf*)(smem + ra * 256 + ((kk ^ (ra & 15)) * 16));
    }
#pragma unroll
    for (int fc = 0; fc < 4; fc++) {
      int rb = wc * 64 + fc * 16 + lr;
      v8hf bh = *(const v8hf*)(smem + OB + rb * 256 + ((kk ^ (rb & 15)) * 16));
#pragma unroll
      for (int fr = 0; fr < 2; fr++)
        acc[fr][fc] = __builtin_amdgcn_mfma_f32_16x16x32_f16(ah[fr], bh, acc[fr][fc], 0, 0, 0);
    }
  }

  u16* op = WxT16 + (size_t)bp * Nx * Gx;
#pragma unroll
  for (int fr = 0; fr < 2; fr++)
#pragma unroll
    for (int fc = 0; fc < 4; fc++) {
      int n = rt * 64 + wr * 32 + fr * 16 + ks * 4;
      int g = wc * 64 + fc * 16 + lr;
#pragma unroll
      for (int q = 0; q < 4; q++) op[(size_t)(n + q) * Gx + g] = f2h(acc[fr][fc][q]);
    }
}

// ---------------------------------------------------------------------------
// attn6: attn4 structure (measured best) with ONE change: pass 3 stores go
// through a slot-rotated LDS transpose T[512][68] then coalesced u32 copy-out.
// grid (B*P, N/64), 512 thr (2 wr x 4 wc waves). Block: 64 i x 512 j, K=128.
// LDS 75776 -> 2 blocks/CU.
// ---------------------------------------------------------------------------
__global__ __launch_bounds__(512) void attn6_kernel(const u16* __restrict__ xT16,
                                                    const u16* __restrict__ WxT16,
                                                    const u32* __restrict__ mb,
                                                    u16* __restrict__ aijT) {
  __shared__ __align__(16) char smem[75776];
  constexpr int OB = 16384, OMBS = 69632, ORED = 73728;
  const int bp = blockIdx.x, b = bp >> 2;
  const int i0 = blockIdx.y * 64;
  const int tid = threadIdx.x;
  const int w = tid >> 6, l = tid & 63;
  const int wr = w >> 2, wc = w & 3;
  const int lr = l & 15, ks = l >> 4;

  {  // mask rows -> LDS (64 rows x 16 words)
    const u32* mbp = mb + ((size_t)b * Nx + i0) * 16;
    u32* mbs = (u32*)(smem + OMBS);
    mbs[tid] = mbp[tid];
    mbs[tid + 512] = mbp[tid + 512];
  }
  {  // stage A: xT16 rows i0..i0+63, full K=128, chunk-XOR (r&15)
    const u16* Ap = xT16 + ((size_t)b * Nx + i0) * Gx;
#pragma unroll
    for (int it = 0; it < 2; it++) {
      int chunk = it * 512 + w * 64 + l;
      int r = chunk >> 4, kq = l & 15;
      int kg = (kq ^ (r & 15)) * 8;
      G2L16(Ap + (size_t)r * Gx + kg, smem + it * 8192 + w * 1024);
    }
  }

  v4f acc[2][8];
#pragma unroll
  for (int fr = 0; fr < 2; fr++)
#pragma unroll
    for (int fc = 0; fc < 8; fc++) acc[fr][fc] = (v4f){0.f, 0.f, 0.f, 0.f};

  const u16* Bp = WxT16 + (size_t)bp * Nx * Gx;
  for (int g0 = 0; g0 < Gx; g0 += 32) {
    __syncthreads();
#pragma unroll
    for (int it = 0; it < 4; it++) {
      int chunk = it * 512 + w * 64 + l;
      int r = chunk >> 2, kq = l & 3;
      int kg = (kq ^ (r & 3)) * 8;
      G2L16(Bp + (size_t)r * Gx + g0 + kg, smem + OB + it * 8192 + w * 1024);
    }
    __syncthreads();
    int kk = (g0 >> 3) + ks;
    v8hf ah[2];
#pragma unroll
    for (int fr = 0; fr < 2; fr++) {
      int ra = wr * 32 + fr * 16 + lr;
      ah[fr] = *(const v8hf*)(smem + ra * 256 + ((kk ^ (ra & 15)) * 16));
    }
#pragma unroll
    for (int fc = 0; fc < 8; fc++) {
      int rb = wc * 128 + fc * 16 + lr;
      v8hf bh = *(const v8hf*)(smem + OB + rb * 64 + ((ks ^ (rb & 3)) * 16));
#pragma unroll
      for (int fr = 0; fr < 2; fr++)
        acc[fr][fc] = __builtin_amdgcn_mfma_f32_16x16x32_f16(ah[fr], bh, acc[fr][fc], 0, 0, 0);
    }
  }

  u32* mbs = (u32*)(smem + OMBS);
  float* red0 = (float*)(smem + ORED);
  float* red1 = red0 + 256;

  // pass 1: masked leaky-relu + cross-wave row max partials
#pragma unroll
  for (int fr = 0; fr < 2; fr++)
#pragma unroll
    for (int q = 0; q < 4; q++) {
      int row = wr * 32 + fr * 16 + ks * 4 + q;
      float m = -BIGF;
#pragma unroll
      for (int fc = 0; fc < 8; fc++) {
        u32 word = mbs[row * 16 + wc * 4 + (fc >> 1)];
        int bit = ((fc & 1) << 4) + lr;
        float v = acc[fr][fc][q];
        v = v >= 0.f ? v : NEG_SLOPE * v;
        v = ((word >> bit) & 1u) ? v : -BIGF;
        acc[fr][fc][q] = v;
        m = fmaxf(m, v);
      }
      m = fmaxf(m, __shfl_xor(m, 1, 64));
      m = fmaxf(m, __shfl_xor(m, 2, 64));
      m = fmaxf(m, __shfl_xor(m, 4, 64));
      m = fmaxf(m, __shfl_xor(m, 8, 64));
      if (lr == 0) red0[row * 4 + wc] = m;
    }
  __syncthreads();
  // pass 2: global max, exp, cross-wave row sum partials
#pragma unroll
  for (int fr = 0; fr < 2; fr++)
#pragma unroll
    for (int q = 0; q < 4; q++) {
      int row = wr * 32 + fr * 16 + ks * 4 + q;
      float4 pm = *(const float4*)&red0[row * 4];
      float gm = fmaxf(fmaxf(pm.x, pm.y), fmaxf(pm.z, pm.w));
      float s = 0.f;
#pragma unroll
      for (int fc = 0; fc < 8; fc++) {
        float v = acc[fr][fc][q];
        float e = (v <= -0.5f * BIGF) ? 0.f : __expf(v - gm);
        acc[fr][fc][q] = e;
        s += e;
      }
      s += __shfl_xor(s, 1, 64);
      s += __shfl_xor(s, 2, 64);
      s += __shfl_xor(s, 4, 64);
      s += __shfl_xor(s, 8, 64);
      if (lr == 0) red1[row * 4 + wc] = s;
    }
  __syncthreads();
  // pass 3: normalize -> LDS transpose T[j][68 u16], slot-rotated, then
  // coalesced u32 copy-out (128B per row-wave).
  char* T = smem;  // overlays dead A+B staging (48KB) and beyond, 69632B
#pragma unroll
  for (int fr = 0; fr < 2; fr++) {
    int rbase = wr * 32 + fr * 16 + ks * 4;
    int slot = rbase >> 2;
    float inv[4];
#pragma unroll
    for (int q = 0; q < 4; q++) {
      float4 ps = *(const float4*)&red1[(rbase + q) * 4];
      float tot = (ps.x + ps.y) + (ps.z + ps.w);
      inv[q] = tot > 0.f ? 1.f / tot : 0.f;
    }
#pragma unroll
    for (int fc = 0; fc < 8; fc++) {
      int j = wc * 128 + fc * 16 + lr;
      ushort4 pk;
      pk.x = f2b(acc[fr][fc][0] * inv[0]);
      pk.y = f2b(acc[fr][fc][1] * inv[1]);
      pk.z = f2b(acc[fr][fc][2] * inv[2]);
      pk.w = f2b(acc[fr][fc][3] * inv[3]);
      int ps2 = (slot + j) & 15;
      *(ushort4*)(T + (size_t)j * 136 + ps2 * 8) = pk;
    }
  }
  __syncthreads();
  u16* dst = aijT + (size_t)bp * Nx * Nx + i0;
#pragma unroll 4
  for (int it = 0; it < 32; it++) {
    int idx = it * 512 + tid;
    int j = idx >> 5, dw = idx & 31;
    int ps2 = ((dw >> 1) + j) & 15;
    u32 v = *(const u32*)(T + (size_t)j * 136 + ps2 * 8 + (dw & 1) * 4);
    *(u32*)&dst[(size_t)j * Nx + dw * 2] = v;
  }
}

// ---------------------------------------------------------------------------
// NT-GEMM core (r7-verified): 2-phase double-buffered, one barrier per K-iter.
// MODE 0: hop1  A=aijT(bp)  B=xb(b)    -> z1[g][m] + z1T[m][g]
// MODE 1: hop2  A=z1(bp)    B=aijT(bp) -> z2T[m][g]
// MODE 2: filt  A={xTb,z1T,z2T} segs  B=Hb(p) -> out[f][n] fp32 (+bias, relu)
// ---------------------------------------------------------------------------
template <int MODE>
__global__ __launch_bounds__(256) void gnt_kernel(const u16* __restrict__ pA,
                                                  const u16* __restrict__ pB,
                                                  const u16* __restrict__ pC,
                                                  const u16* __restrict__ pHb,
                                                  u16* __restrict__ o1,
                                                  u16* __restrict__ o2,
                                                  float* __restrict__ oF,
                                                  const float* __restrict__ bias) {
  __shared__ __align__(16) char smem[2][12288];
  const int bp = blockIdx.x;
  const int b = bp >> 2, p = bp & 3;
  const int by = blockIdx.y;
  const int rt = (MODE == 1) ? (by >> 2) : by;
  const int ct = (MODE == 1) ? (by & 3) : 0;
  const int tid = threadIdx.x;
  const int w = tid >> 6, l = tid & 63;
  const int wr = w >> 1, wc = w & 1;
  const int lr = l & 15, kslot = l >> 4;

  constexpr int KTOT = (MODE == 2) ? (Kx * Gx) : Nx;
  constexpr int SA = (MODE == 2) ? Gx : Nx;
  constexpr int SB = (MODE == 2) ? (Kx * Gx) : Nx;
  constexpr int NT = KTOT / 32;

  const u16* Abase;
  const u16* Bbase;
  if (MODE == 0) {
    Abase = pA + (size_t)bp * Nx * Nx + (size_t)rt * 64 * Nx;
    Bbase = pB + (size_t)b * Gx * Nx;
  } else if (MODE == 1) {
    Abase = pA + (size_t)bp * Gx * Nx + (size_t)rt * 64 * Nx;
    Bbase = pB + (size_t)bp * Nx * Nx + (size_t)ct * 128 * Nx;
  } else {
    Abase = nullptr;
    Bbase = pHb + (size_t)p * Fx * (Kx * Gx);
  }

  const int sar = tid >> 2;
  const int sakg = (tid & 3) ^ (sar & 3);
  const int sbr0 = tid >> 2, sbkg0 = (tid & 3) ^ (sbr0 & 3);
  const int sbr1 = (tid + 256) >> 2, sbkg1 = (tid & 3) ^ (sbr1 & 3);

  int aoff[2], boff[4];
#pragma unroll
  for (int fr = 0; fr < 2; fr++) {
    int row = wr * 32 + fr * 16 + lr;
    aoff[fr] = row * 64 + ((kslot ^ (row & 3)) * 16);
  }
#pragma unroll
  for (int fc = 0; fc < 4; fc++) {
    int row = wc * 64 + fc * 16 + lr;
    boff[fc] = 4096 + row * 64 + ((kslot ^ (row & 3)) * 16);
  }

  auto STAGE = [&](int bufi, int k0) {
    const u16* Aseg;
    int kin;
    if (MODE == 2) {
      int seg = k0 >> 7;
      kin = k0 & 127;
      const u16* base = (seg == 0) ? (pA + (size_t)b * Nx * Gx)
                       : (seg == 1) ? (pB + (size_t)bp * Nx * Gx)
                                    : (pC + (size_t)bp * Nx * Gx);
      Aseg = base + (size_t)rt * 64 * Gx;
    } else {
      Aseg = Abase;
      kin = k0;
    }
    char* base = smem[bufi];
    G2L16(Aseg + (size_t)sar * SA + kin + sakg * 8, base + w * 1024);
    G2L16(Bbase + (size_t)sbr0 * SB + k0 + sbkg0 * 8, base + 4096 + w * 1024);
    G2L16(Bbase + (size_t)sbr1 * SB + k0 + sbkg1 * 8, base + 8192 + w * 1024);
  };

  v4f acc[2][4];
#pragma unroll
  for (int fr = 0; fr < 2; fr++)
#pragma unroll
    for (int fc = 0; fc < 4; fc++) acc[fr][fc] = (v4f){0.f, 0.f, 0.f, 0.f};

  STAGE(0, 0);
  int cur = 0;
  for (int t = 0; t < NT; t++) {
    __syncthreads();
    if (t + 1 < NT) STAGE(cur ^ 1, (t + 1) * 32);
    const char* bb = smem[cur];
    v8bf af[2], bf4[4];
#pragma unroll
    for (int fr = 0; fr < 2; fr++) af[fr] = *(const v8bf*)(bb + aoff[fr]);
#pragma unroll
    for (int fc = 0; fc < 4; fc++) bf4[fc] = *(const v8bf*)(bb + boff[fc]);
#pragma unroll
    for (int fr = 0; fr < 2; fr++)
#pragma unroll
      for (int fc = 0; fc < 4; fc++)
        acc[fr][fc] = __builtin_amdgcn_mfma_f32_16x16x32_bf16(af[fr], bf4[fc],
                                                              acc[fr][fc], 0, 0, 0);
    cur ^= 1;
  }

  if (MODE == 0) {
    u16* z1p = o1 + (size_t)bp * Gx * Nx;
    u16* z1Tp = o2 + (size_t)bp * Nx * Gx;
#pragma unroll
    for (int fr = 0; fr < 2; fr++)
#pragma unroll
      for (int fc = 0; fc < 4; fc++) {
        int m0 = rt * 64 + wr * 32 + fr * 16 + kslot * 4;
        int g = wc * 64 + fc * 16 + lr;
        v4f a = acc[fr][fc];
        ushort4 pk;
        pk.x = f2b(a[0]); pk.y = f2b(a[1]); pk.z = f2b(a[2]); pk.w = f2b(a[3]);
        *(ushort4*)&z1p[(size_t)g * Nx + m0] = pk;
        z1Tp[(size_t)(m0 + 0) * Gx + g] = pk.x;
        z1Tp[(size_t)(m0 + 1) * Gx + g] = pk.y;
        z1Tp[(size_t)(m0 + 2) * Gx + g] = pk.z;
        z1Tp[(size_t)(m0 + 3) * Gx + g] = pk.w;
      }
  } else if (MODE == 1) {
    u16* z2Tp = o1 + (size_t)bp * Nx * Gx;
#pragma unroll
    for (int fr = 0; fr < 2; fr++)
#pragma unroll
      for (int fc = 0; fc < 4; fc++) {
        int g0r = rt * 64 + wr * 32 + fr * 16 + kslot * 4;
        int m = ct * 128 + wc * 64 + fc * 16 + lr;
        v4f a = acc[fr][fc];
        ushort4 pk;
        pk.x = f2b(a[0]); pk.y = f2b(a[1]); pk.z = f2b(a[2]); pk.w = f2b(a[3]);
        *(ushort4*)&z2Tp[(size_t)m * Gx + g0r] = pk;
      }
  } else {
    float* op = oF + (size_t)(b * Px + p) * Fx * Nx;
#pragma unroll
    for (int fc = 0; fc < 4; fc++) {
      int f = wc * 64 + fc * 16 + lr;
      float bi = bias[f];
#pragma unroll
      for (int fr = 0; fr < 2; fr++) {
        int n0 = rt * 64 + wr * 32 + fr * 16 + kslot * 4;
        v4f a = acc[fr][fc];
        float4 o;
        o.x = fmaxf(a[0] + bi, 0.f);
        o.y = fmaxf(a[1] + bi, 0.f);
        o.z = fmaxf(a[2] + bi, 0.f);
        o.w = fmaxf(a[3] + bi, 0.f);
        *(float4*)&op[(size_t)f * Nx + n0] = o;
      }
    }
  }
}

// ---------------------------------------------------------------------------
extern "C" void kernel_launch(void* const* d_in, const int* in_sizes, int n_in,
                              void* d_out, int out_size, void* d_ws, size_t ws_size,
                              hipStream_t stream) {
  const float* x = (const float*)d_in[0];
  const float* S = (const float*)d_in[1];
  const float* W = (const float*)d_in[2];
  const float* h = (const float*)d_in[4];
  const float* bias = (const float*)d_in[5];
  float* out = (float*)d_out;

  char* ws = (char*)d_ws;
  u16* aijT  = (u16*)ws;                   // @ 0          33,554,432
  u16* WxT16 = (u16*)(ws + 33554432);      // @ 32M         8,388,608
  u16* xT16  = (u16*)(ws + 41943040);      // @ 40M         2,097,152
  u16* xTb   = (u16*)(ws + 44040192);      // @ 42M         2,097,152
  u16* xb    = (u16*)(ws + 46137344);      // @ 44M         2,097,152
  u16* z1    = (u16*)(ws + 48234496);      // @ 46M         8,388,608
  u16* z1T   = (u16*)(ws + 56623104);      // @ 54M         8,388,608
  u16* z2T   = (u16*)(ws + 65011712);      // @ 62M         8,388,608
  u16* Hb    = (u16*)(ws + 73400320);      // @ 70M           393,216
  u16* W16   = (u16*)(ws + 73793536);      //                 131,072
  u32* mb    = (u32*)(ws + 73924608);      //                 524,288

  prep_kernel<<<dim3(1792), 256, 0, stream>>>(S, x, W, h, mb, xb, xTb, xT16, W16, Hb);
  wxt16_kernel<<<dim3(Bx * Px, Nx / 64), 256, 0, stream>>>(xT16, W16, WxT16);
  attn6_kernel<<<dim3(Bx * Px, Nx / 64), 512, 0, stream>>>(xT16, WxT16, mb, aijT);
  gnt_kernel<0><<<dim3(Bx * Px, 8), 256, 0, stream>>>(aijT, xb, nullptr, nullptr,
                                                      z1, z1T, nullptr, nullptr);
  gnt_kernel<1><<<dim3(Bx * Px, 8), 256, 0, stream>>>(z1, aijT, nullptr, nullptr,
                                                      z2T, nullptr, nullptr, nullptr);
  gnt_kernel<2><<<dim3(Bx * Px, 8), 256, 0, stream>>>(xTb, z1T, z2T, Hb,
                                                      nullptr, nullptr, out, bias);
  (void)in_sizes; (void)n_in; (void)out_size; (void)ws_size;
}